// Round 1
// baseline (199.708 us; speedup 1.0000x reference)
//
#include <hip/hip_runtime.h>
#include <hip/hip_bf16.h>
#include <math.h>

#define NBINS 10
#define NVALS 22  // 0:bce 1:nvalid 2..11:counts 12..21:sum((p-t)*w)

__device__ __forceinline__ void proc_elem(float x0, float t0,
                                          float& bce_acc, float* sumd,
                                          unsigned* ucnt, unsigned& uvalid) {
  bool valid = !(x0 != x0 || t0 != t0);
  float x = valid ? x0 : 0.f;
  float t = valid ? t0 : 0.f;
  t = fminf(fmaxf(t, 0.f), 1.f);
  float w = valid ? 1.f : 0.f;

  // softplus(-x) = max(-x,0) + log(1 + exp(-|x|))
  float ax = fabsf(x);
  float e = __expf(-ax);                      // exp(-|x|) in (0,1]
  float sp = __logf(1.f + e) + fmaxf(-x, 0.f);
  float bce = (1.f - t) * x + (80.f * t + (1.f - t)) * sp;
  bce_acc += bce * w;

  // sigmoid(x): 1/(1+e) if x>=0 else e/(1+e)
  float r = __builtin_amdgcn_rcpf(1.f + e);
  float p = (x >= 0.f) ? r : e * r;
  int bin = (int)(p * 10.f);
  bin = bin > 9 ? 9 : bin;
  int binv = valid ? bin : 255;   // invalid elements hit no bin
  float d = (p - t) * w;

  uvalid += (unsigned)__popcll(__ballot(valid));
#pragma unroll
  for (int b = 0; b < NBINS; ++b) {
    unsigned long long m = __ballot(binv == b);
    ucnt[b] += (unsigned)__popcll(m);          // wave-uniform, SALU
    sumd[b] += (binv == b) ? d : 0.f;          // per-lane
  }
}

__global__ __launch_bounds__(256) void dl_partial(
    const float* __restrict__ pred, const float* __restrict__ targ,
    long long n, float* __restrict__ ws, int grid) {
  const int tid = threadIdx.x;
  const long long gid = (long long)blockIdx.x * blockDim.x + tid;
  const long long stride = (long long)grid * blockDim.x;
  const long long nvec = n >> 2;

  float bce_acc = 0.f;
  float sumd[NBINS];
  unsigned ucnt[NBINS];
  unsigned uvalid = 0;
#pragma unroll
  for (int b = 0; b < NBINS; ++b) { sumd[b] = 0.f; ucnt[b] = 0u; }

  const float4* p4 = (const float4*)pred;
  const float4* t4 = (const float4*)targ;
  for (long long i = gid; i < nvec; i += stride) {
    float4 xv = p4[i];
    float4 tv = t4[i];
    proc_elem(xv.x, tv.x, bce_acc, sumd, ucnt, uvalid);
    proc_elem(xv.y, tv.y, bce_acc, sumd, ucnt, uvalid);
    proc_elem(xv.z, tv.z, bce_acc, sumd, ucnt, uvalid);
    proc_elem(xv.w, tv.w, bce_acc, sumd, ucnt, uvalid);
  }
  // scalar tail (active lanes form a prefix, so lane0 is active whenever
  // any lane in its wave is -> ballot counts stay correct in lane0's copy)
  long long tbase = nvec << 2;
  long long ti = tbase + gid;
  if (ti < n) {
    proc_elem(pred[ti], targ[ti], bce_acc, sumd, ucnt, uvalid);
  }

  // pack: wave-uniform ballot counts contribute from lane0 only
  float vals[NVALS];
  const int lane = tid & 63;
  vals[0] = bce_acc;
  vals[1] = (lane == 0) ? (float)uvalid : 0.f;
#pragma unroll
  for (int b = 0; b < NBINS; ++b) {
    vals[2 + b] = (lane == 0) ? (float)ucnt[b] : 0.f;
    vals[12 + b] = sumd[b];
  }
#pragma unroll
  for (int v = 0; v < NVALS; ++v) {
#pragma unroll
    for (int off = 32; off; off >>= 1) vals[v] += __shfl_xor(vals[v], off, 64);
  }

  __shared__ float red[4][NVALS];
  const int wave = tid >> 6;
  if (lane == 0) {
#pragma unroll
    for (int v = 0; v < NVALS; ++v) red[wave][v] = vals[v];
  }
  __syncthreads();
  if (tid < NVALS) {
    float s = red[0][tid] + red[1][tid] + red[2][tid] + red[3][tid];
    ws[(long long)tid * grid + blockIdx.x] = s;  // SoA: row-major by value
  }
}

__global__ __launch_bounds__(256) void dl_final(const float* __restrict__ ws,
                                                float* __restrict__ out,
                                                int grid) {
  __shared__ double totals[NVALS];
  __shared__ double wred[4];
  const int tid = threadIdx.x;
  for (int r = 0; r < NVALS; ++r) {
    double psum = 0.0;
    for (int i = tid; i < grid; i += 256)
      psum += (double)ws[(long long)r * grid + i];
#pragma unroll
    for (int off = 32; off; off >>= 1) psum += __shfl_xor(psum, off, 64);
    if ((tid & 63) == 0) wred[tid >> 6] = psum;
    __syncthreads();
    if (tid == 0) totals[r] = wred[0] + wred[1] + wred[2] + wred[3];
    __syncthreads();
  }
  if (tid == 0) {
    double bce = totals[0], nv = totals[1];
    double dist = 0.0;
    for (int b = 0; b < NBINS; ++b) {
      double c = totals[2 + b], sd = totals[12 + b];
      double safe = c > 1.0 ? c : 1.0;
      if (c > 10.0) dist += fabs(sd) / safe;
    }
    double loss = bce / nv + dist / (double)NBINS * 0.2;
    out[0] = (float)loss;
  }
}

extern "C" void kernel_launch(void* const* d_in, const int* in_sizes, int n_in,
                              void* d_out, int out_size, void* d_ws, size_t ws_size,
                              hipStream_t stream) {
  const float* pred = (const float*)d_in[0];
  const float* targ = (const float*)d_in[1];
  const long long n = (long long)in_sizes[0];
  float* out = (float*)d_out;
  float* ws = (float*)d_ws;

  int grid = 2048;  // 256 CUs x 8 blocks -> saturates HBM
  while (grid > 64 && (size_t)NVALS * grid * sizeof(float) > ws_size) grid >>= 1;

  dl_partial<<<grid, 256, 0, stream>>>(pred, targ, n, ws, grid);
  dl_final<<<1, 256, 0, stream>>>(ws, out, grid);
}

// Round 2
// 148.885 us; speedup vs baseline: 1.3414x; 1.3414x over previous
//
#include <hip/hip_runtime.h>
#include <hip/hip_bf16.h>
#include <math.h>

#define NBINS 10
#define NVALS 21          // 0:bce, 1..10:counts, 11..20:sum((p-t)*w)
#define THREADS 256
#define PAD_PAIRS 11      // 10 (sumd,cnt) pairs + 1 pad pair -> 22 words stride
                          // 22*l mod 32 spreads b64 accesses to the 128/32=4
                          // per-bank minimum (gcd analysis; see journal)

// Per-element work. LDS slot `my` holds 10 float2 {sumd, cnt} pairs.
__device__ __forceinline__ void proc(float x0, float t0, float& bce_acc,
                                     float2* __restrict__ my) {
  bool valid = (x0 == x0) && (t0 == t0);
  float x = valid ? x0 : 0.f;
  float t = valid ? __builtin_amdgcn_fmed3f(t0, 0.f, 1.f) : 0.f;
  float w = valid ? 1.f : 0.f;

  // softplus(-x) = max(-x,0) + log(1 + exp(-|x|))
  float e = __expf(-fabsf(x));            // v_mul(log2e) + v_exp
  float L = 1.f + e;
  float sp = __logf(L) + fmaxf(-x, 0.f);  // v_log + v_mul(ln2) + max + add
  float a = 1.f - t;
  float coef = __builtin_fmaf(79.f, t, 1.f);        // 80t + (1-t)
  float bce = __builtin_fmaf(coef, sp, a * x);
  bce_acc = __builtin_fmaf(bce, w, bce_acc);

  // sigmoid via the already-computed e, L
  float r = __builtin_amdgcn_rcpf(L);
  float p = (x >= 0.f) ? r : e * r;
  int bin = (int)(p * 10.f);
  bin = bin > 9 ? 9 : bin;
  float d = (p - t) * w;

  float2 v = my[bin];       // ds_read_b64
  v.x += d;
  v.y += w;
  my[bin] = v;              // ds_write_b64
}

__global__ __launch_bounds__(THREADS) void dl_partial(
    const float* __restrict__ pred, const float* __restrict__ targ,
    long long n, float* __restrict__ ws, int grid) {
  __shared__ float hist[THREADS * PAD_PAIRS * 2];
  __shared__ float red[4][NVALS];

  const int tid = threadIdx.x;
  float2* my = (float2*)(hist + tid * (PAD_PAIRS * 2));  // 88B stride, 8B aligned
#pragma unroll
  for (int b = 0; b < NBINS; ++b) my[b] = make_float2(0.f, 0.f);

  const long long gid = (long long)blockIdx.x * THREADS + tid;
  const long long stride = (long long)grid * THREADS;
  const long long nvec = n >> 2;

  float bce_acc = 0.f;
  const float4* p4 = (const float4*)pred;
  const float4* t4 = (const float4*)targ;
  for (long long i = gid; i < nvec; i += stride) {
    float4 xv = p4[i];
    float4 tv = t4[i];
    proc(xv.x, tv.x, bce_acc, my);
    proc(xv.y, tv.y, bce_acc, my);
    proc(xv.z, tv.z, bce_acc, my);
    proc(xv.w, tv.w, bce_acc, my);
  }
  long long ti = (nvec << 2) + gid;
  if (ti < n) proc(pred[ti], targ[ti], bce_acc, my);

  // gather own slots (no sync needed: private data), then block-reduce
  float vals[NVALS];
  vals[0] = bce_acc;
#pragma unroll
  for (int b = 0; b < NBINS; ++b) {
    float2 v = my[b];
    vals[1 + b] = v.y;        // count
    vals[11 + b] = v.x;       // sum (p-t)*w
  }
#pragma unroll
  for (int v = 0; v < NVALS; ++v) {
#pragma unroll
    for (int off = 32; off; off >>= 1) vals[v] += __shfl_xor(vals[v], off, 64);
  }
  const int lane = tid & 63;
  const int wave = tid >> 6;
  if (lane == 0) {
#pragma unroll
    for (int v = 0; v < NVALS; ++v) red[wave][v] = vals[v];
  }
  __syncthreads();
  if (tid < NVALS) {
    float s = red[0][tid] + red[1][tid] + red[2][tid] + red[3][tid];
    ws[(long long)tid * grid + blockIdx.x] = s;  // SoA for coalesced final pass
  }
}

__global__ __launch_bounds__(THREADS) void dl_final(
    const float* __restrict__ ws, float* __restrict__ out, int grid) {
  __shared__ double totals[NVALS];
  __shared__ double wred[4];
  const int tid = threadIdx.x;
  for (int r = 0; r < NVALS; ++r) {
    double psum = 0.0;
    for (int i = tid; i < grid; i += THREADS)
      psum += (double)ws[(long long)r * grid + i];
#pragma unroll
    for (int off = 32; off; off >>= 1) psum += __shfl_xor(psum, off, 64);
    if ((tid & 63) == 0) wred[tid >> 6] = psum;
    __syncthreads();
    if (tid == 0) totals[r] = wred[0] + wred[1] + wred[2] + wred[3];
    __syncthreads();
  }
  if (tid == 0) {
    double bce = totals[0];
    double nv = 0.0;
    for (int b = 0; b < NBINS; ++b) nv += totals[1 + b];  // n_valid = sum of bin counts
    double dist = 0.0;
    for (int b = 0; b < NBINS; ++b) {
      double c = totals[1 + b], sd = totals[11 + b];
      double safe = c > 1.0 ? c : 1.0;
      if (c > 10.0) dist += fabs(sd) / safe;
    }
    out[0] = (float)(bce / nv + dist / (double)NBINS * 0.2);
  }
}

extern "C" void kernel_launch(void* const* d_in, const int* in_sizes, int n_in,
                              void* d_out, int out_size, void* d_ws, size_t ws_size,
                              hipStream_t stream) {
  const float* pred = (const float*)d_in[0];
  const float* targ = (const float*)d_in[1];
  const long long n = (long long)in_sizes[0];
  float* out = (float*)d_out;
  float* ws = (float*)d_ws;

  int grid = 1792;  // 7 blocks/CU x 256 CUs (LDS-capped at 7: 22.9 KB/block)
  while (grid > 64 && (size_t)NVALS * grid * sizeof(float) > ws_size) grid >>= 1;

  dl_partial<<<grid, THREADS, 0, stream>>>(pred, targ, n, ws, grid);
  dl_final<<<1, THREADS, 0, stream>>>(ws, out, grid);
}